// Round 2
// baseline (237.610 us; speedup 1.0000x reference)
//
#include <hip/hip_runtime.h>
#include <stdint.h>

// MFMA fragment types (gfx950)
typedef __attribute__((ext_vector_type(8))) short short8;  // 8 bf16 = 4 VGPRs
typedef __attribute__((ext_vector_type(4))) float f32x4;   // 4 fp32 acc / vec load

static_assert(sizeof(short8) == 16, "frag size");

__device__ __forceinline__ uint16_t f2bf(float f) {
  uint32_t u = __builtin_bit_cast(uint32_t, f);
  u += 0x7fffu + ((u >> 16) & 1u);
  return (uint16_t)(u >> 16);
}

__device__ __forceinline__ void gload_lds16(const void* g, void* lds_wave_base) {
  // async global->LDS, 16B/lane; LDS dst = wave-uniform base + lane*16
  __builtin_amdgcn_global_load_lds(
      (__attribute__((address_space(1))) void*)(void*)(g),
      (__attribute__((address_space(3))) void*)(lds_wave_base),
      16, 0, 0);
}

// compile-time memory reorder fence: pins VMEM/DS issue order around it
#define MEMFENCE() asm volatile("" ::: "memory")

// Swizzle convention (all bf16 staging): within each 64-elem K-group, 16B
// chunk c of row r is stored at chunk c ^ (r&7) (XOR touches bits 0-2 only,
// composing transparently with any BK). DMA stages tiles verbatim; fragment
// reads at chunk (h*4+q)^(r&7) are conflict-free ds_read_b128.

// ---------------------------------------------------------------------------
// quant: dwT[o][i] = ternary(weight[i][o]) in {-1,0,+1} bf16, swizzled.
// ---------------------------------------------------------------------------
__global__ __launch_bounds__(256) void quant_kernel(const float* __restrict__ w,
                                                    uint16_t* __restrict__ dwT) {
  const int o = blockIdx.x, i = threadIdx.x;
  const float v = w[i * 256 + o];
  const float t = (v > 0.01f) ? 1.0f : ((v < -0.01f) ? -1.0f : 0.0f);
  dwT[o * 256 + (i ^ ((o & 7) << 3))] = f2bf(t);
}

// ---------------------------------------------------------------------------
// support (SINGLE-PASS K=256): spt[o][g] = bf16(0.01 * sum_i x[g][i]*tern[i][o])
// Tile [64 g][64 o], full K staged once (A 32 KB + B 32 KB = 64 KB LDS,
// 2 blocks/CU). Grid 1024 = 256 g-tiles x 4 o-tiles. 3 barriers/block total.
// ---------------------------------------------------------------------------
#define SB_A 0       // [64 g][256 i] bf16 swizzled, 32768 B (reused in epilogue)
#define SB_B 32768   // [64 o][256 i] bf16 swizzled, 32768 B

__global__ __launch_bounds__(256) void support_kernel(const float* __restrict__ x,
                                                      const uint16_t* __restrict__ dwT,
                                                      uint16_t* __restrict__ spt) {
  __shared__ __align__(16) unsigned char smem[65536];
  const int t = threadIdx.x, lane = t & 63, w = t >> 6;
  const int r = lane & 15, q = lane >> 4;
  const int g0 = (blockIdx.x & 255) * 64;
  const int o0 = (blockIdx.x >> 8) * 64;

  // stage A: x [64 g][256 i] fp32 -> bf16, packed b128 swizzled writes
#pragma unroll
  for (int j = 0; j < 8; ++j) {
    const int id = j * 256 + t;              // 64 rows x 32 chunks = 2048 ids
    const int row = id >> 5, c = id & 31;
    const float* p = x + (size_t)(g0 + row) * 256 + c * 8;
    const f32x4 v0 = *(const f32x4*)p;
    const f32x4 v1 = *(const f32x4*)(p + 4);
    uint4 u;
    u.x = (uint32_t)f2bf(v0.x) | ((uint32_t)f2bf(v0.y) << 16);
    u.y = (uint32_t)f2bf(v0.z) | ((uint32_t)f2bf(v0.w) << 16);
    u.z = (uint32_t)f2bf(v1.x) | ((uint32_t)f2bf(v1.y) << 16);
    u.w = (uint32_t)f2bf(v1.z) | ((uint32_t)f2bf(v1.w) << 16);
    *(uint4*)(smem + SB_A + row * 512 + ((c ^ (row & 7)) << 4)) = u;
  }
  // stage B: dwT rows [o0,o0+64) full K, verbatim DMA (pre-swizzled)
#pragma unroll
  for (int j = 0; j < 8; ++j) {
    const int id = j * 256 + t, row = id >> 5, c = id & 31;
    gload_lds16(dwT + (size_t)(o0 + row) * 256 + c * 8,
                smem + SB_B + (size_t)(j * 256 + w * 64) * 16);
  }
  __syncthreads();

  f32x4 acc[4] = {};
#pragma unroll
  for (int h = 0; h < 8; ++h) {              // K=256 in 8 steps of 32
    short8 av, bv[4];
    const int pc = (((h * 4 + q) ^ (r & 7)) << 4);
    av = *(const short8*)(smem + SB_A + (16 * w + r) * 512 + pc);
#pragma unroll
    for (int ni = 0; ni < 4; ++ni)
      bv[ni] = *(const short8*)(smem + SB_B + (16 * ni + r) * 512 + pc);
#pragma unroll
    for (int ni = 0; ni < 4; ++ni)
      acc[ni] = __builtin_amdgcn_mfma_f32_16x16x32_bf16(av, bv[ni], acc[ni], 0, 0, 0);
  }
  __syncthreads();   // all waves' LDS reads done before transpose overwrite

  // epilogue: transpose buffer [64 o][64 g] bf16 (8 KB, reuses SB_A region)
#pragma unroll
  for (int ni = 0; ni < 4; ++ni) {
    const int ol = 16 * ni + r;              // C col = o
#pragma unroll
    for (int reg = 0; reg < 4; ++reg) {
      const int gl = 16 * w + 4 * q + reg;   // C row = g
      const int gsw = gl ^ ((ol & 7) << 3);  // global col swizzle
      *(uint16_t*)(smem + (ol * 64 + gsw) * 2) = f2bf(acc[ni][reg] * 0.01f);
    }
  }
  __syncthreads();
  // copy out: 64 rows x 8 chunks of 16 B, coalesced dwordx4
#pragma unroll
  for (int it = 0; it < 2; ++it) {
    const int id = it * 256 + t, row = id >> 3, cc = id & 7;
    const uint4 u = *(const uint4*)(smem + (row * 64 + cc * 8) * 2);
    *(uint4*)(spt + (size_t)(o0 + row) * 16384 + g0 + cc * 8) = u;
  }
}

// ---------------------------------------------------------------------------
// main v3 (counted-vmcnt pipeline, BK=128, dbuf): out = relu(adj@support+bias)
// Tile [32 n][256 o], K=2048 in BK=128 steps (16 iters).
// Key change vs v1/v2: NO __syncthreads in the K-loop. Raw s_barrier with
// manual "s_waitcnt vmcnt(4) lgkmcnt(0)" so the 4 adj (A) register-prefetch
// loads for tile t+2 stay IN FLIGHT across barriers (HBM stream never
// drains). A-prefetch is per-wave registers -> no cross-wave hazard. B-DMA
// (L2-resident spt) is depth-1 and IS drained by vmcnt(4) before each
// barrier, so every LDS buffer is complete before its readers pass the
// barrier. Issue order pinned by MEMFENCE so the count "4 newest = A(t+2)"
// is exact:  [B-DMA(t+1) x8] then [A(t+2) x4] per step.
// Per-step wait audit (steady state, issue-ordered oldest->newest):
//   A(t+1)x4 | B(t+1)x8 | A(t+2)x4      (16 outstanding after issue)
//   - convert A(t+1): compiler auto-emits vmcnt(12)
//   - pre-barrier:    vmcnt(4) drains B(t+1), keeps A(t+2); lgkmcnt(0)
//     drains my ds_write; s_barrier => buf[nxt] complete for all readers.
// Tail: kt=14 issues no A -> vmcnt(0); kt=15 computes only.
// ---------------------------------------------------------------------------
#define MB_A0 0       // [32][128] bf16 swizzled, 8192 B
#define MB_A1 8192
#define MB_B0 16384   // [256][128] bf16, 32768 B... (rows of 256B; 65536 B)
#define MB_B1 81920

__global__ __launch_bounds__(256) void gcn_main_kernel(const float* __restrict__ adj,
                                                       const uint16_t* __restrict__ spt,
                                                       const float* __restrict__ bias,
                                                       float* __restrict__ out) {
  // A: 2 x 8 KB, B: 2 x 64 KB -> 144 KB? No: B tile [256][128] bf16 = 64 KB.
  // 2*(8+64) = 144 KB > 1 block/CU. Use B row-halves per wave as before:
  // actually [256 o][128 m] bf16 = 256*128*2 = 65536 B. Double buffer won't
  // fit 2 blocks/CU at 144 KB. So: A dbuf (2x8KB) + B dbuf of HALF-K?
  // Resolution: keep BK=128 but B single... -> instead BK=128 with B row
  // stride 256B and both buffers: 16K + 128K = 144K, 1 block/CU (4 waves).
  // That kills occupancy. Choose BK=64-equivalent footprint: stage B in two
  // K-halves per step is the old shape. Final choice: BK=128 for A (regs
  // pipeline + LDS 2x8KB) and B double-buffered at 2x32KB by splitting each
  // 128-K step into two 64-K halves staged back-to-back (B dbuf granularity
  // 64). LDS = 16K + 64K = 80K -> 2 blocks/CU.
  __shared__ __align__(16) unsigned char smem[81920];
  const int t = threadIdx.x, lane = t & 63, w = t >> 6;
  const int r = lane & 15, q = lane >> 4;
  const int bb = blockIdx.x & 7;             // batch -> XCD affinity
  const int n0 = (blockIdx.x >> 3) * 32;     // n-tile
  const float* adjb = adj + ((size_t)bb * 2048 + n0) * 2048;
  const uint16_t* sptb = spt + (size_t)bb * 2048;

  // A staging: [32 n][128 m] bf16 per tile, 512 chunks of 16B; 256 threads ->
  // 2 chunks/thread: chunk ids t and t+256 (row, row+16; same col swizzle).
  const int aRow = t >> 4, aC = t & 15;
  const float* aP0 = adjb + (size_t)aRow * 2048 + aC * 8;          // row
  const float* aP1 = aP0 + (size_t)16 * 2048;                      // row+16
  const unsigned aOff0 = aRow * 256 + ((aC ^ (aRow & 7)) << 4);
  const unsigned aOff1 = aOff0 + 16 * 256;

  // B staging: [256 o][64 m] bf16 per half-step = 32 KB, 2048 chunks, DMA.
  // buffers: BH0 @16384, BH1 @49152 (2 x 32 KB)
#define MB_BH0 16384u
#define MB_BH1 49152u

#define B_DMA(K0, BOFF)                                                        \
  do {                                                                         \
    _Pragma("unroll") for (int j = 0; j < 8; ++j) {                            \
      const int id = j * 256 + t, row_ = id >> 3, c_ = id & 7;                 \
      gload_lds16(sptb + (size_t)row_ * 16384 + (K0) + c_ * 8,                 \
                  smem + (BOFF) + (size_t)(j * 256 + w * 64) * 16);            \
    }                                                                          \
  } while (0)

#define A_LOAD(K0, R0, R1, S0, S1)                                             \
  do {                                                                         \
    R0 = *(const f32x4*)(aP0 + (K0));                                          \
    S0 = *(const f32x4*)(aP0 + (K0) + 4);                                      \
    R1 = *(const f32x4*)(aP1 + (K0));                                          \
    S1 = *(const f32x4*)(aP1 + (K0) + 4);                                      \
  } while (0)

#define A_WRITE(AOFF, R0, S0, R1, S1)                                          \
  do {                                                                         \
    uint4 u0, u1;                                                              \
    u0.x = (uint32_t)f2bf(R0.x) | ((uint32_t)f2bf(R0.y) << 16);                \
    u0.y = (uint32_t)f2bf(R0.z) | ((uint32_t)f2bf(R0.w) << 16);                \
    u0.z = (uint32_t)f2bf(S0.x) | ((uint32_t)f2bf(S0.y) << 16);                \
    u0.w = (uint32_t)f2bf(S0.z) | ((uint32_t)f2bf(S0.w) << 16);                \
    u1.x = (uint32_t)f2bf(R1.x) | ((uint32_t)f2bf(R1.y) << 16);                \
    u1.y = (uint32_t)f2bf(R1.z) | ((uint32_t)f2bf(R1.w) << 16);                \
    u1.z = (uint32_t)f2bf(S1.x) | ((uint32_t)f2bf(S1.y) << 16);                \
    u1.w = (uint32_t)f2bf(S1.z) | ((uint32_t)f2bf(S1.w) << 16);                \
    *(uint4*)(smem + (AOFF) + aOff0) = u0;                                     \
    *(uint4*)(smem + (AOFF) + aOff1) = u1;                                     \
  } while (0)

  // A-tile here is [32 n][64 m] per half-step (4 KB): chunk/thread = 1? Keep
  // A at 64-K granularity too: per half-step each thread loads 8 floats of
  // its row segment. Rework: with K-half hk, thread covers (row, 8 floats).
  // 32 rows x 8 chunks = 256 ids -> exactly 1 chunk/thread.
#undef A_LOAD
#undef A_WRITE
  const int a64Row = t >> 3, a64C = t & 7;
  const float* a64P = adjb + (size_t)a64Row * 2048 + a64C * 8;
  const unsigned a64Off = a64Row * 128 + ((a64C ^ (a64Row & 7)) << 4);
  // A buffers: 2 x 4 KB @ 0 and 4096? MB_A region is 16 KB: use 0 / 4096.
#define MB_AH0 0u
#define MB_AH1 4096u

  f32x4 acc[2][4] = {};

  // ---- prologue: stage half-tile 0 (k=0..63) into buf0; prefetch A half 1
  MEMFENCE();
  B_DMA(0, MB_BH0);
  MEMFENCE();
  f32x4 p0 = *(const f32x4*)(a64P);          // A half 0
  f32x4 p1 = *(const f32x4*)(a64P + 4);
  MEMFENCE();
  f32x4 n0v = *(const f32x4*)(a64P + 64);    // A half 1 (prefetch)
  f32x4 n1v = *(const f32x4*)(a64P + 68);
  MEMFENCE();
  {
    uint4 u;
    u.x = (uint32_t)f2bf(p0.x) | ((uint32_t)f2bf(p0.y) << 16);
    u.y = (uint32_t)f2bf(p0.z) | ((uint32_t)f2bf(p0.w) << 16);
    u.z = (uint32_t)f2bf(p1.x) | ((uint32_t)f2bf(p1.y) << 16);
    u.w = (uint32_t)f2bf(p1.z) | ((uint32_t)f2bf(p1.w) << 16);
    *(uint4*)(smem + MB_AH0 + a64Off) = u;   // auto vmcnt(2): drains B0+A0
  }
  asm volatile("s_waitcnt vmcnt(2) lgkmcnt(0)" ::: "memory");
  __builtin_amdgcn_s_barrier();
  p0 = n0v; p1 = n1v;

  // ---- main loop over 32 half-steps of K=64
  for (int kt = 0; kt < 32; ++kt) {
    const int cur = kt & 1;
    const unsigned aCur = cur ? MB_AH1 : MB_AH0;
    const unsigned bCur = cur ? MB_BH1 : MB_BH0;
    const unsigned aNxt = cur ? MB_AH0 : MB_AH1;
    const unsigned bNxt = cur ? MB_BH0 : MB_BH1;
    const int k1 = (kt + 1) * 64;

    if (kt < 31) {                           // B-DMA for half-step t+1
      MEMFENCE();
      B_DMA(k1, bNxt);
      MEMFENCE();
    }
    f32x4 q0, q1;
    if (kt < 30) {                           // A regs for half-step t+2
      q0 = *(const f32x4*)(a64P + (kt + 2) * 64);
      q1 = *(const f32x4*)(a64P + (kt + 2) * 64 + 4);
      MEMFENCE();
    }

    // compute current half-step from buf[cur]
#pragma unroll
    for (int h = 0; h < 2; ++h) {            // 2 k-slices of 32
      short8 av[2], bv[4];
      const int pc = (((h * 4 + q) ^ (r & 7)) << 4);
#pragma unroll
      for (int mi = 0; mi < 2; ++mi)
        av[mi] = *(const short8*)(smem + aCur + (16 * mi + r) * 128 + pc);
#pragma unroll
      for (int ni = 0; ni < 4; ++ni)
        bv[ni] = *(const short8*)(smem + bCur + (w * 64 + 16 * ni + r) * 128 + pc);
#pragma unroll
      for (int mi = 0; mi < 2; ++mi)
#pragma unroll
        for (int ni = 0; ni < 4; ++ni)
          acc[mi][ni] = __builtin_amdgcn_mfma_f32_16x16x32_bf16(av[mi], bv[ni],
                                                                acc[mi][ni], 0, 0, 0);
    }

    if (kt < 31) {                           // convert+write A(t+1) late
      uint4 u;                               // compiler auto-waits p0/p1
      u.x = (uint32_t)f2bf(p0.x) | ((uint32_t)f2bf(p0.y) << 16);
      u.y = (uint32_t)f2bf(p0.z) | ((uint32_t)f2bf(p0.w) << 16);
      u.z = (uint32_t)f2bf(p1.x) | ((uint32_t)f2bf(p1.y) << 16);
      u.w = (uint32_t)f2bf(p1.z) | ((uint32_t)f2bf(p1.w) << 16);
      *(uint4*)(smem + aNxt + a64Off) = u;
      if (kt < 30) {
        // keep the 2 newest (A(t+2)) in flight; drain B(t+1) + my ds_write
        asm volatile("s_waitcnt vmcnt(2) lgkmcnt(0)" ::: "memory");
      } else {
        asm volatile("s_waitcnt vmcnt(0) lgkmcnt(0)" ::: "memory");
      }
      __builtin_amdgcn_s_barrier();
      p0 = q0; p1 = q1;
    }
  }

  // epilogue: +bias, relu, fp32 store
#pragma unroll
  for (int ni = 0; ni < 4; ++ni) {
    const int o = w * 64 + 16 * ni + r;      // C col = N = o
    const float bs = bias[o];
#pragma unroll
    for (int mi = 0; mi < 2; ++mi)
#pragma unroll
      for (int reg = 0; reg < 4; ++reg) {
        const int n = n0 + 16 * mi + 4 * q + reg;  // C row = M = n
        out[((size_t)bb * 2048 + n) * 256 + o] = fmaxf(acc[mi][ni][reg] + bs, 0.0f);
      }
  }
}

// ---------------------------------------------------------------------------
extern "C" void kernel_launch(void* const* d_in, const int* in_sizes, int n_in,
                              void* d_out, int out_size, void* d_ws, size_t ws_size,
                              hipStream_t stream) {
  const float* x      = (const float*)d_in[0];  // [8,2048,256]
  const float* adj    = (const float*)d_in[1];  // [8,2048,2048]
  const float* weight = (const float*)d_in[2];  // [256,256]
  const float* bias   = (const float*)d_in[3];  // [256]
  float* out = (float*)d_out;                   // [8,2048,256]

  uint16_t* dwT = (uint16_t*)d_ws;                          // 128 KB
  uint16_t* spt = (uint16_t*)((char*)d_ws + 131072);        // 8 MB

  hipLaunchKernelGGL(quant_kernel,    dim3(256),  dim3(256), 0, stream, weight, dwT);
  hipLaunchKernelGGL(support_kernel,  dim3(1024), dim3(256), 0, stream, x, dwT, spt);
  hipLaunchKernelGGL(gcn_main_kernel, dim3(512),  dim3(256), 0, stream, adj, spt, bias, out);
}